// Round 7
// baseline (161.416 us; speedup 1.0000x reference)
//
#include <hip/hip_runtime.h>
#include <hip/hip_bf16.h>

#define BB 4
#define SS 32
#define HH 8
#define LL 128
#define DD 512
#define DI 2048
#define EPSN 1e-6f
#define INV_TEMP 0.04419417382415922f   // 1/sqrt(512)

#define NLOGW_BLK 512                    // 2048 wave-tasks: (l, bs-group-of-8)
#define NCAST_GRAN ((DI*DD/4)*2 + (DD*DD/4))   // 589824 float4 granules
#define NCAST_BLK (NCAST_GRAN / 256)     // 2304

#define NROW (BB*SS*HH)                  // 1024 rows
#define SLICE ((size_t)NROW * DD)        // floats per K-split partial
#define NAVL_BLK 64                      // attn_v_ln: 16 rows (2 bs) per block

typedef __attribute__((ext_vector_type(8))) short short8;
typedef __attribute__((ext_vector_type(4))) float float4v;

static __device__ __forceinline__ unsigned short f2b(float f) {
  __hip_bfloat16 h = __float2bfloat16(f);
  return *(unsigned short*)&h;
}

// Fragment-packed layout (r10-proven): element (m,k) of an (M x K) operand at
//   ((((m>>4)*(K/32) + (k>>5))*4 + ((k>>3)&3))*16 + (m&15))*8 + (k&7)
// -> one MFMA fragment = one contiguous 1 KB wave read.
static __device__ __forceinline__ size_t pk(int m, int k, int K) {
  return ((((size_t)(m >> 4) * (K >> 5) + (k >> 5)) * 4 + ((k >> 3) & 3)) * 16
          + (m & 15)) * 8 + (k & 7);
}

// ---------------------------------------------------------------------------
// K1: fused [logits] + [weight cast -> fragment-packed bf16].  (r13, proven)
// ---------------------------------------------------------------------------
__global__ __launch_bounds__(256) void pre_kernel(
    const float* __restrict__ x, const int* __restrict__ mask,
    const float* __restrict__ w, const float* __restrict__ w1,
    const float* __restrict__ w2, const float* __restrict__ v_w,
    unsigned short* __restrict__ w1b, unsigned short* __restrict__ w2b,
    unsigned short* __restrict__ v_wb, float* __restrict__ logits) {
  int blk = blockIdx.x;
  if (blk < NLOGW_BLK) {
    int wv = threadIdx.x >> 6, lane = threadIdx.x & 63;
    int p   = blk * 4 + wv;          // 0..2047
    int l   = p >> 4;                // 0..127
    int bsg = p & 15;                // bs group: 8 consecutive bs

    float4 wr[HH][2];
#pragma unroll
    for (int h = 0; h < HH; ++h) {
      const float4* wp = (const float4*)(w + ((size_t)h * LL + l) * DD) + lane * 2;
      wr[h][0] = wp[0];
      wr[h][1] = wp[1];
    }

#pragma unroll 2
    for (int i = 0; i < 8; ++i) {
      int bs = bsg * 8 + i;
      const float4* xr = (const float4*)(x + ((size_t)bs * LL + l) * DD) + lane * 2;
      float4 x0 = xr[0], x1 = xr[1];
      float acc[HH];
#pragma unroll
      for (int h = 0; h < HH; ++h) {
        acc[h] = x0.x * wr[h][0].x + x0.y * wr[h][0].y +
                 x0.z * wr[h][0].z + x0.w * wr[h][0].w +
                 x1.x * wr[h][1].x + x1.y * wr[h][1].y +
                 x1.z * wr[h][1].z + x1.w * wr[h][1].w;
      }
#pragma unroll
      for (int off = 32; off > 0; off >>= 1) {
#pragma unroll
        for (int h = 0; h < HH; ++h) acc[h] += __shfl_xor(acc[h], off);
      }
      if (lane == 0) {
        int msk = mask[bs * LL + l];
#pragma unroll
        for (int h = 0; h < HH; ++h) {
          float lg = msk ? acc[h] * INV_TEMP : -1e9f;
          logits[((size_t)bs * HH + h) * LL + l] = lg;
        }
      }
    }
  } else {
    const int n1 = (DI * DD) / 4;    // w1 granules (N=2048,K=512)
    const int n2 = n1;               // w2 granules (N=512, K=2048)
    int i = (blk - NLOGW_BLK) * 256 + threadIdx.x;
    float4 v;
    unsigned short* dst;
    size_t base;
    if (i < n1) {
      v = ((const float4*)w1)[i];
      dst = w1b;
      base = pk(i >> 7, (i & 127) * 4, DD);
    } else if (i < n1 + n2) {
      int j = i - n1;
      v = ((const float4*)w2)[j];
      dst = w2b;
      base = pk(j >> 9, (j & 511) * 4, DI);
    } else {
      int j = i - n1 - n2;
      v = ((const float4*)v_w)[j];
      dst = v_wb;
      base = pk(j >> 7, (j & 127) * 4, DD);
    }
    dst[base + 0] = f2b(v.x);
    dst[base + 1] = f2b(v.y);
    dst[base + 2] = f2b(v.z);
    dst[base + 3] = f2b(v.w);
  }
}

// ---------------------------------------------------------------------------
// K2: fused softmax + xa contraction + GEMM_V (full K=512) + mid-LN.
// Phase 2 = r1-proven scalar form. Phase 3 B-loads 2-deep register dbuf.
// ---------------------------------------------------------------------------
__global__ __launch_bounds__(512) void attn_v_ln_kernel(
    const float* __restrict__ x, const float* __restrict__ logits,
    const unsigned short* __restrict__ v_wb, const float* __restrict__ ln_g,
    const float* __restrict__ ln_b, float* __restrict__ attn_out,
    float* __restrict__ o_ln, unsigned short* __restrict__ o_lnb) {
  int blk = blockIdx.x;            // 0..63
  int t = threadIdx.x, wv = t >> 6, lane = t & 63;
  int bs0 = blk * 2;               // rows blk*16 .. blk*16+15 = bs pair

  __shared__ __align__(16) float sattnT[LL][20];
  __shared__ __align__(16) unsigned short apk[16 * DD];  // packed A frags, 16 KB
  __shared__ float wstat[8][16][2];
  __shared__ float rstat[16][2];

  // ---- Phase 1: softmax (wave wv owns rows 2wv, 2wv+1) ----
#pragma unroll
  for (int rr = 0; rr < 2; ++rr) {
    int r = wv * 2 + rr;
    int bs = bs0 + (r >> 3), h = r & 7;
    const float* lg = logits + ((size_t)bs * HH + h) * LL;
    float v0 = lg[lane], v1 = lg[lane + 64];
    float m = fmaxf(v0, v1);
#pragma unroll
    for (int off = 32; off > 0; off >>= 1) m = fmaxf(m, __shfl_xor(m, off));
    float e0 = __expf(v0 - m), e1 = __expf(v1 - m);
    float s = e0 + e1;
#pragma unroll
    for (int off = 32; off > 0; off >>= 1) s += __shfl_xor(s, off);
    float inv = 1.f / s;
    e0 *= inv; e1 *= inv;
    sattnT[lane][r]      = e0;
    sattnT[lane + 64][r] = e1;
    float* ao = attn_out + ((size_t)bs * HH + h) * LL;
    ao[lane]      = e0;
    ao[lane + 64] = e1;
  }
  __syncthreads();

  // ---- Phase 2: xa[m][e] = sum_l attn[m][l] * x[bs(m),l,e]  (r1 scalar) ----
  {
    int e = t;                                   // 0..511
    const float* xb = x + (size_t)bs0 * LL * DD + e;
    float acc[16];
#pragma unroll
    for (int m = 0; m < 16; ++m) acc[m] = 0.f;
#pragma unroll 2
    for (int l = 0; l < LL; l += 4) {
      float xv0[4], xv1[4];
#pragma unroll
      for (int j = 0; j < 4; ++j) {
        xv0[j] = xb[(size_t)(l + j) * DD];
        xv1[j] = xb[(size_t)(LL + l + j) * DD];
      }
#pragma unroll
      for (int j = 0; j < 4; ++j) {
        float4 a0 = *(const float4*)&sattnT[l + j][0];
        float4 a1 = *(const float4*)&sattnT[l + j][4];
        float4 a2 = *(const float4*)&sattnT[l + j][8];
        float4 a3 = *(const float4*)&sattnT[l + j][12];
        acc[0]  += a0.x * xv0[j]; acc[1]  += a0.y * xv0[j];
        acc[2]  += a0.z * xv0[j]; acc[3]  += a0.w * xv0[j];
        acc[4]  += a1.x * xv0[j]; acc[5]  += a1.y * xv0[j];
        acc[6]  += a1.z * xv0[j]; acc[7]  += a1.w * xv0[j];
        acc[8]  += a2.x * xv1[j]; acc[9]  += a2.y * xv1[j];
        acc[10] += a2.z * xv1[j]; acc[11] += a2.w * xv1[j];
        acc[12] += a3.x * xv1[j]; acc[13] += a3.y * xv1[j];
        acc[14] += a3.z * xv1[j]; acc[15] += a3.w * xv1[j];
      }
    }
    unsigned base = ((e >> 5) * 4 + ((e >> 3) & 3)) * 128 + (e & 7);
#pragma unroll
    for (int m = 0; m < 16; ++m) apk[base + m * 8] = f2b(acc[m]);
  }
  __syncthreads();

  // ---- Phase 3: GEMM_V (16 x 512, K=512), 2-deep B prefetch ----
  int lm = lane & 15, lq = lane >> 4;
  int n0 = wv * 64;
  const short8* A8 = (const short8*)apk;
  const short8* B8 = (const short8*)v_wb;
  float4v acc3[4];
#pragma unroll
  for (int nf = 0; nf < 4; ++nf) acc3[nf] = (float4v){0.f, 0.f, 0.f, 0.f};

  short8 b_p[2][4];
#pragma unroll
  for (int s = 0; s < 2; ++s)
#pragma unroll
    for (int nf = 0; nf < 4; ++nf)
      b_p[s][nf] = B8[((size_t)((n0 >> 4) + nf) * 16 + s) * 64 + lane];

#pragma unroll
  for (int c = 0; c < 16; ++c) {
    const int pc = c & 1;
    short8 b_n[4];
    if (c < 14) {
#pragma unroll
      for (int nf = 0; nf < 4; ++nf)
        b_n[nf] = B8[((size_t)((n0 >> 4) + nf) * 16 + (c + 2)) * 64 + lane];
    }
    short8 a = A8[c * 64 + lane];
#pragma unroll
    for (int nf = 0; nf < 4; ++nf)
      acc3[nf] = __builtin_amdgcn_mfma_f32_16x16x32_bf16(a, b_p[pc][nf], acc3[nf], 0, 0, 0);
    if (c < 14) {
#pragma unroll
      for (int nf = 0; nf < 4; ++nf) b_p[pc][nf] = b_n[nf];
    }
  }

  // ---- Phase 4: block-local LayerNorm ----
  float srow[4], qrow[4];
#pragma unroll
  for (int r = 0; r < 4; ++r) {
    float s = 0.f, q = 0.f;
#pragma unroll
    for (int nf = 0; nf < 4; ++nf) { float v = acc3[nf][r]; s += v; q += v * v; }
#pragma unroll
    for (int off = 1; off < 16; off <<= 1) {
      s += __shfl_xor(s, off);
      q += __shfl_xor(q, off);
    }
    srow[r] = s; qrow[r] = q;
  }
  if (lm == 0) {
#pragma unroll
    for (int r = 0; r < 4; ++r) {
      wstat[wv][lq * 4 + r][0] = srow[r];
      wstat[wv][lq * 4 + r][1] = qrow[r];
    }
  }
  __syncthreads();
  if (t < 16) {
    float S = 0.f, Q = 0.f;
#pragma unroll
    for (int w8 = 0; w8 < 8; ++w8) { S += wstat[w8][t][0]; Q += wstat[w8][t][1]; }
    float mu  = S * (1.f / DD);
    float var = Q * (1.f / DD) - mu * mu;
    rstat[t][0] = mu;
    rstat[t][1] = rsqrtf(var + EPSN);
  }
  __syncthreads();
#pragma unroll
  for (int nf = 0; nf < 4; ++nf) {
    int col = n0 + nf * 16 + lm;
    float g = ln_g[col], bcol = ln_b[col];
#pragma unroll
    for (int r = 0; r < 4; ++r) {
      int row = lq * 4 + r;
      float v = (acc3[nf][r] - rstat[row][0]) * rstat[row][1] * g + bcol;
      int grow = blk * 16 + row;
      o_ln[(size_t)grow * DD + col] = v;
      o_lnb[pk(grow, col, DD)] = f2b(v);
    }
  }
}

// ---------------------------------------------------------------------------
// K3: GEMM1  h1 = relu(xln @ w1^T + b1) -> h1b.  2-deep A/B register dbuf:
// full unroll keeps all buffer indices compile-time (no scratch).
// ---------------------------------------------------------------------------
__global__ __launch_bounds__(256) void gemm1_kernel(
    const unsigned short* __restrict__ o_lnb, const unsigned short* __restrict__ w1b,
    const float* __restrict__ b1, unsigned short* __restrict__ h1b) {
  int blk = blockIdx.x;
  int nt = blk & 31, mt = blk >> 5;
  int wv = threadIdx.x >> 6, lane = threadIdx.x & 63;
  int lm = lane & 15, lq = lane >> 4;

  int m0 = mt * 64 + wv * 16;
  int n0 = nt * 64;
  const short8* A8 = (const short8*)o_lnb + (size_t)(m0 >> 4) * 16 * 64;
  const short8* B8 = (const short8*)w1b;

  float4v acc[4];
#pragma unroll
  for (int nf = 0; nf < 4; ++nf) acc[nf] = (float4v){0.f, 0.f, 0.f, 0.f};

  short8 a_p[2], b_p[2][4];
#pragma unroll
  for (int s = 0; s < 2; ++s) {
    a_p[s] = A8[(size_t)s * 64 + lane];
#pragma unroll
    for (int nf = 0; nf < 4; ++nf)
      b_p[s][nf] = B8[((size_t)((n0 >> 4) + nf) * 16 + s) * 64 + lane];
  }

#pragma unroll
  for (int c = 0; c < 16; ++c) {
    const int pc = c & 1;
    short8 a_n, b_n[4];
    if (c < 14) {
      a_n = A8[(size_t)(c + 2) * 64 + lane];
#pragma unroll
      for (int nf = 0; nf < 4; ++nf)
        b_n[nf] = B8[((size_t)((n0 >> 4) + nf) * 16 + (c + 2)) * 64 + lane];
    }
#pragma unroll
    for (int nf = 0; nf < 4; ++nf)
      acc[nf] = __builtin_amdgcn_mfma_f32_16x16x32_bf16(a_p[pc], b_p[pc][nf], acc[nf], 0, 0, 0);
    if (c < 14) {
      a_p[pc] = a_n;
#pragma unroll
      for (int nf = 0; nf < 4; ++nf) b_p[pc][nf] = b_n[nf];
    }
  }

#pragma unroll
  for (int nf = 0; nf < 4; ++nf) {
    int col = n0 + nf * 16 + lm;
    float bb = b1[col];
#pragma unroll
    for (int r = 0; r < 4; ++r) {
      int row = m0 + lq * 4 + r;
      h1b[pk(row, col, DI)] = f2b(fmaxf(acc[nf][r] + bb, 0.f));
    }
  }
}

// ---------------------------------------------------------------------------
// K4: GEMM2  ypart[ks] = h1 @ w2^T.  K-split x4, 2-deep A/B register dbuf.
// ---------------------------------------------------------------------------
__global__ __launch_bounds__(256) void gemm2_kernel(
    const unsigned short* __restrict__ h1b, const unsigned short* __restrict__ w2b,
    float* __restrict__ ypart) {
  int blk = blockIdx.x;
  int nt = blk & 7, mt = (blk >> 3) & 15, kslice = blk >> 7;
  int wv = threadIdx.x >> 6, lane = threadIdx.x & 63;
  int lm = lane & 15, lq = lane >> 4;

  int m0 = mt * 64 + wv * 16;
  int n0 = nt * 64;
  const short8* A8 = (const short8*)h1b + (size_t)(m0 >> 4) * 64 * 64;   // K/32=64
  const short8* B8 = (const short8*)w2b;
  const int c0 = kslice * 16;

  float4v acc[4];
#pragma unroll
  for (int nf = 0; nf < 4; ++nf) acc[nf] = (float4v){0.f, 0.f, 0.f, 0.f};

  short8 a_p[2], b_p[2][4];
#pragma unroll
  for (int s = 0; s < 2; ++s) {
    a_p[s] = A8[(size_t)(c0 + s) * 64 + lane];
#pragma unroll
    for (int nf = 0; nf < 4; ++nf)
      b_p[s][nf] = B8[((size_t)((n0 >> 4) + nf) * 64 + (c0 + s)) * 64 + lane];
  }

#pragma unroll
  for (int ci = 0; ci < 16; ++ci) {
    const int pc = ci & 1;
    short8 a_n, b_n[4];
    if (ci < 14) {
      a_n = A8[(size_t)(c0 + ci + 2) * 64 + lane];
#pragma unroll
      for (int nf = 0; nf < 4; ++nf)
        b_n[nf] = B8[((size_t)((n0 >> 4) + nf) * 64 + (c0 + ci + 2)) * 64 + lane];
    }
#pragma unroll
    for (int nf = 0; nf < 4; ++nf)
      acc[nf] = __builtin_amdgcn_mfma_f32_16x16x32_bf16(a_p[pc], b_p[pc][nf], acc[nf], 0, 0, 0);
    if (ci < 14) {
      a_p[pc] = a_n;
#pragma unroll
      for (int nf = 0; nf < 4; ++nf) b_p[pc][nf] = b_n[nf];
    }
  }

  float* outp = ypart + (size_t)kslice * SLICE;
#pragma unroll
  for (int nf = 0; nf < 4; ++nf) {
    int col = n0 + nf * 16 + lm;
#pragma unroll
    for (int r = 0; r < 4; ++r)
      outp[(size_t)(m0 + lq * 4 + r) * DD + col] = acc[nf][r];
  }
}

// ---------------------------------------------------------------------------
// K5: final LN:  y = LN(sum ypart + b2 + o_ln)*g + b.  (r10)
// ---------------------------------------------------------------------------
__global__ __launch_bounds__(256) void ln_final_kernel(
    const float* __restrict__ ypart, const float* __restrict__ o_ln,
    const float* __restrict__ b2, const float* __restrict__ fln_g,
    const float* __restrict__ fln_b, float* __restrict__ y_out) {
  int wv = threadIdx.x >> 6, lane = threadIdx.x & 63;
  int row = blockIdx.x * 4 + wv;

  const float* p0 = ypart + (size_t)row * DD;
  const float* ol = o_ln + (size_t)row * DD;
  float vals[8];
  float sum = 0.f, sq = 0.f;
#pragma unroll
  for (int k = 0; k < 8; ++k) {
    int d = lane + 64 * k;
    float v = p0[d] + p0[SLICE + d] + p0[2 * SLICE + d] + p0[3 * SLICE + d] +
              b2[d] + ol[d];
    vals[k] = v;
    sum += v;
    sq += v * v;
  }
#pragma unroll
  for (int off = 32; off > 0; off >>= 1) {
    sum += __shfl_xor(sum, off);
    sq  += __shfl_xor(sq, off);
  }
  float mu  = sum * (1.f / DD);
  float var = sq * (1.f / DD) - mu * mu;
  float rs  = rsqrtf(var + EPSN);
  float* yo = y_out + (size_t)row * DD;
#pragma unroll
  for (int k = 0; k < 8; ++k) {
    int d = lane + 64 * k;
    yo[d] = (vals[k] - mu) * rs * fln_g[d] + fln_b[d];
  }
}

extern "C" void kernel_launch(void* const* d_in, const int* in_sizes, int n_in,
                              void* d_out, int out_size, void* d_ws, size_t ws_size,
                              hipStream_t stream) {
  const float* x     = (const float*)d_in[0];
  const int*   mask  = (const int*)d_in[1];
  const float* w     = (const float*)d_in[2];
  const float* v_w   = (const float*)d_in[3];
  const float* ln_g  = (const float*)d_in[4];
  const float* ln_b  = (const float*)d_in[5];
  const float* w1    = (const float*)d_in[6];
  const float* b1    = (const float*)d_in[7];
  const float* w2    = (const float*)d_in[8];
  const float* b2    = (const float*)d_in[9];
  const float* fln_g = (const float*)d_in[10];
  const float* fln_b = (const float*)d_in[11];

  float* y    = (float*)d_out;
  float* attn = y + (size_t)BB * SS * HH * DD;

  // workspace layout (bytes)
  char* ws = (char*)d_ws;
  float*          o_ln   = (float*)(ws);                       // 2 MB
  unsigned short* o_lnb  = (unsigned short*)(ws + 2097152);    // 1 MB
  unsigned short* w1b    = (unsigned short*)(ws + 3145728);    // 2 MB
  unsigned short* w2b    = (unsigned short*)(ws + 5242880);    // 2 MB
  unsigned short* h1b    = (unsigned short*)(ws + 7340032);    // 4 MB
  float*          ypart  = (float*)(ws + 11534336);            // 8 MB (4 slices)
  unsigned short* v_wb   = (unsigned short*)(ws + 19922944);   // 512 KB
  float*          logits = (float*)(ws + 29884416);            // 512 KB

  pre_kernel<<<NLOGW_BLK + NCAST_BLK, 256, 0, stream>>>(
      x, mask, w, w1, w2, v_w, w1b, w2b, v_wb, logits);
  attn_v_ln_kernel<<<NAVL_BLK, 512, 0, stream>>>(
      x, logits, v_wb, ln_g, ln_b, attn, o_ln, o_lnb);
  gemm1_kernel<<<512, 256, 0, stream>>>(o_lnb, w1b, b1, h1b);
  gemm2_kernel<<<512, 256, 0, stream>>>(h1b, w2b, ypart);
  ln_final_kernel<<<256, 256, 0, stream>>>(ypart, o_ln, b2, fln_g, fln_b, y);
}

// Round 8
// 155.729 us; speedup vs baseline: 1.0365x; 1.0365x over previous
//
#include <hip/hip_runtime.h>
#include <hip/hip_bf16.h>

#define BB 4
#define SS 32
#define HH 8
#define LL 128
#define DD 512
#define DI 2048
#define EPSN 1e-6f
#define INV_TEMP 0.04419417382415922f   // 1/sqrt(512)

#define NLOGW_BLK 512                    // 2048 wave-tasks: (l, bs-group-of-8)
#define NCAST_GRAN ((DI*DD/4)*2 + (DD*DD/4))   // 589824 float4 granules
#define NCAST_BLK (NCAST_GRAN / 256)     // 2304

#define NROW (BB*SS*HH)                  // 1024 rows
#define SLICE ((size_t)NROW * DD)        // floats per K-split partial
#define NAVL_BLK 128                     // attn_v_ln: 1 bs (8 rows) per block

typedef __attribute__((ext_vector_type(8))) short short8;
typedef __attribute__((ext_vector_type(4))) float float4v;

static __device__ __forceinline__ unsigned short f2b(float f) {
  __hip_bfloat16 h = __float2bfloat16(f);
  return *(unsigned short*)&h;
}

// Fragment-packed layout (r10-proven): element (m,k) of an (M x K) operand at
//   ((((m>>4)*(K/32) + (k>>5))*4 + ((k>>3)&3))*16 + (m&15))*8 + (k&7)
// -> one MFMA fragment = one contiguous 1 KB wave read.
static __device__ __forceinline__ size_t pk(int m, int k, int K) {
  return ((((size_t)(m >> 4) * (K >> 5) + (k >> 5)) * 4 + ((k >> 3) & 3)) * 16
          + (m & 15)) * 8 + (k & 7);
}

// ---------------------------------------------------------------------------
// K1: fused [logits] + [weight cast -> fragment-packed bf16].  (r13, proven)
// ---------------------------------------------------------------------------
__global__ __launch_bounds__(256) void pre_kernel(
    const float* __restrict__ x, const int* __restrict__ mask,
    const float* __restrict__ w, const float* __restrict__ w1,
    const float* __restrict__ w2, const float* __restrict__ v_w,
    unsigned short* __restrict__ w1b, unsigned short* __restrict__ w2b,
    unsigned short* __restrict__ v_wb, float* __restrict__ logits) {
  int blk = blockIdx.x;
  if (blk < NLOGW_BLK) {
    int wv = threadIdx.x >> 6, lane = threadIdx.x & 63;
    int p   = blk * 4 + wv;          // 0..2047
    int l   = p >> 4;                // 0..127
    int bsg = p & 15;                // bs group: 8 consecutive bs

    float4 wr[HH][2];
#pragma unroll
    for (int h = 0; h < HH; ++h) {
      const float4* wp = (const float4*)(w + ((size_t)h * LL + l) * DD) + lane * 2;
      wr[h][0] = wp[0];
      wr[h][1] = wp[1];
    }

#pragma unroll 2
    for (int i = 0; i < 8; ++i) {
      int bs = bsg * 8 + i;
      const float4* xr = (const float4*)(x + ((size_t)bs * LL + l) * DD) + lane * 2;
      float4 x0 = xr[0], x1 = xr[1];
      float acc[HH];
#pragma unroll
      for (int h = 0; h < HH; ++h) {
        acc[h] = x0.x * wr[h][0].x + x0.y * wr[h][0].y +
                 x0.z * wr[h][0].z + x0.w * wr[h][0].w +
                 x1.x * wr[h][1].x + x1.y * wr[h][1].y +
                 x1.z * wr[h][1].z + x1.w * wr[h][1].w;
      }
#pragma unroll
      for (int off = 32; off > 0; off >>= 1) {
#pragma unroll
        for (int h = 0; h < HH; ++h) acc[h] += __shfl_xor(acc[h], off);
      }
      if (lane == 0) {
        int msk = mask[bs * LL + l];
#pragma unroll
        for (int h = 0; h < HH; ++h) {
          float lg = msk ? acc[h] * INV_TEMP : -1e9f;
          logits[((size_t)bs * HH + h) * LL + l] = lg;
        }
      }
    }
  } else {
    const int n1 = (DI * DD) / 4;    // w1 granules (N=2048,K=512)
    const int n2 = n1;               // w2 granules (N=512, K=2048)
    int i = (blk - NLOGW_BLK) * 256 + threadIdx.x;
    float4 v;
    unsigned short* dst;
    size_t base;
    if (i < n1) {
      v = ((const float4*)w1)[i];
      dst = w1b;
      base = pk(i >> 7, (i & 127) * 4, DD);
    } else if (i < n1 + n2) {
      int j = i - n1;
      v = ((const float4*)w2)[j];
      dst = w2b;
      base = pk(j >> 9, (j & 511) * 4, DI);
    } else {
      int j = i - n1 - n2;
      v = ((const float4*)v_w)[j];
      dst = v_wb;
      base = pk(j >> 7, (j & 127) * 4, DD);
    }
    dst[base + 0] = f2b(v.x);
    dst[base + 1] = f2b(v.y);
    dst[base + 2] = f2b(v.z);
    dst[base + 3] = f2b(v.w);
  }
}

// ---------------------------------------------------------------------------
// K2: fused softmax + xa contraction + GEMM_V + mid-LN.
// NOW 128 blocks, ONE bs (8 rows) per block -> 2x CU coverage vs r1.
// M=16 MFMA tile zero-padded in rows 8..15 (zero A-rows -> zero C-rows,
// never stored). Per-(m,e) fp32 summation order identical to r1.
// ---------------------------------------------------------------------------
__global__ __launch_bounds__(512) void attn_v_ln_kernel(
    const float* __restrict__ x, const float* __restrict__ logits,
    const unsigned short* __restrict__ v_wb, const float* __restrict__ ln_g,
    const float* __restrict__ ln_b, float* __restrict__ attn_out,
    float* __restrict__ o_ln, unsigned short* __restrict__ o_lnb) {
  int bs = blockIdx.x;             // 0..127: rows bs*8 .. bs*8+7
  int t = threadIdx.x, wv = t >> 6, lane = t & 63;

  __shared__ __align__(16) float sattnT[LL][20];         // cols 0..7 used
  __shared__ __align__(16) unsigned short apk[16 * DD];  // packed A frags, 16 KB
  __shared__ float wstat[8][8][2];
  __shared__ float rstat[8][2];

  // ---- Phase 1: softmax (wave wv owns row h = wv) ----
  {
    int h = wv;
    const float* lg = logits + ((size_t)bs * HH + h) * LL;
    float v0 = lg[lane], v1 = lg[lane + 64];
    float m = fmaxf(v0, v1);
#pragma unroll
    for (int off = 32; off > 0; off >>= 1) m = fmaxf(m, __shfl_xor(m, off));
    float e0 = __expf(v0 - m), e1 = __expf(v1 - m);
    float s = e0 + e1;
#pragma unroll
    for (int off = 32; off > 0; off >>= 1) s += __shfl_xor(s, off);
    float inv = 1.f / s;
    e0 *= inv; e1 *= inv;
    sattnT[lane][h]      = e0;
    sattnT[lane + 64][h] = e1;
    float* ao = attn_out + ((size_t)bs * HH + h) * LL;
    ao[lane]      = e0;
    ao[lane + 64] = e1;
  }
  __syncthreads();

  // ---- Phase 2: xa[h][e] = sum_l attn[h][l] * x[bs,l,e]  (fp32) ----
  {
    int e = t;                                   // 0..511
    const float* xb = x + (size_t)bs * LL * DD + e;
    float acc[8];
#pragma unroll
    for (int h = 0; h < 8; ++h) acc[h] = 0.f;
#pragma unroll 4
    for (int l = 0; l < LL; ++l) {
      float xv = xb[(size_t)l * DD];
      float4 a0 = *(const float4*)&sattnT[l][0];
      float4 a1 = *(const float4*)&sattnT[l][4];
      acc[0] += a0.x * xv; acc[1] += a0.y * xv;
      acc[2] += a0.z * xv; acc[3] += a0.w * xv;
      acc[4] += a1.x * xv; acc[5] += a1.y * xv;
      acc[6] += a1.z * xv; acc[7] += a1.w * xv;
    }
    unsigned base = ((e >> 5) * 4 + ((e >> 3) & 3)) * 128 + (e & 7);
#pragma unroll
    for (int h = 0; h < 8; ++h) apk[base + h * 8] = f2b(acc[h]);
#pragma unroll
    for (int h = 8; h < 16; ++h) apk[base + h * 8] = 0;   // zero-pad rows 8..15
  }
  __syncthreads();

  // ---- Phase 3: GEMM_V (16(x8 valid) x 512, K=512); wave wv: cols wv*64 ----
  int lm = lane & 15, lq = lane >> 4;
  int n0 = wv * 64;
  const short8* A8 = (const short8*)apk;
  const short8* B8 = (const short8*)v_wb;
  float4v acc3[4];
#pragma unroll
  for (int nf = 0; nf < 4; ++nf) acc3[nf] = (float4v){0.f, 0.f, 0.f, 0.f};
#pragma unroll 4
  for (int c = 0; c < 16; ++c) {
    short8 a = A8[c * 64 + lane];
#pragma unroll
    for (int nf = 0; nf < 4; ++nf) {
      short8 b = B8[((size_t)((n0 >> 4) + nf) * 16 + c) * 64 + lane];
      acc3[nf] = __builtin_amdgcn_mfma_f32_16x16x32_bf16(a, b, acc3[nf], 0, 0, 0);
    }
  }

  // ---- Phase 4: block-local LayerNorm over 512 cols of the 8 valid rows ----
  float srow[4], qrow[4];
#pragma unroll
  for (int r = 0; r < 4; ++r) {
    float s = 0.f, q = 0.f;
#pragma unroll
    for (int nf = 0; nf < 4; ++nf) { float v = acc3[nf][r]; s += v; q += v * v; }
#pragma unroll
    for (int off = 1; off < 16; off <<= 1) {
      s += __shfl_xor(s, off);
      q += __shfl_xor(q, off);
    }
    srow[r] = s; qrow[r] = q;
  }
  if (lm == 0 && lq < 2) {
#pragma unroll
    for (int r = 0; r < 4; ++r) {
      wstat[wv][lq * 4 + r][0] = srow[r];
      wstat[wv][lq * 4 + r][1] = qrow[r];
    }
  }
  __syncthreads();
  if (t < 8) {
    float S = 0.f, Q = 0.f;
#pragma unroll
    for (int w8 = 0; w8 < 8; ++w8) { S += wstat[w8][t][0]; Q += wstat[w8][t][1]; }
    float mu  = S * (1.f / DD);
    float var = Q * (1.f / DD) - mu * mu;
    rstat[t][0] = mu;
    rstat[t][1] = rsqrtf(var + EPSN);
  }
  __syncthreads();
  if (lq < 2) {
#pragma unroll
    for (int nf = 0; nf < 4; ++nf) {
      int col = n0 + nf * 16 + lm;
      float g = ln_g[col], bcol = ln_b[col];
#pragma unroll
      for (int r = 0; r < 4; ++r) {
        int row = lq * 4 + r;
        float v = (acc3[nf][r] - rstat[row][0]) * rstat[row][1] * g + bcol;
        int grow = bs * 8 + row;
        o_ln[(size_t)grow * DD + col] = v;
        o_lnb[pk(grow, col, DD)] = f2b(v);
      }
    }
  }
}

// ---------------------------------------------------------------------------
// K3: GEMM1  h1 = relu(xln @ w1^T + b1) -> h1b (packed, A-role K=2048). (r10)
// ---------------------------------------------------------------------------
__global__ __launch_bounds__(256) void gemm1_kernel(
    const unsigned short* __restrict__ o_lnb, const unsigned short* __restrict__ w1b,
    const float* __restrict__ b1, unsigned short* __restrict__ h1b) {
  int blk = blockIdx.x;
  int nt = blk & 31, mt = blk >> 5;
  int wv = threadIdx.x >> 6, lane = threadIdx.x & 63;
  int lm = lane & 15, lq = lane >> 4;

  int m0 = mt * 64 + wv * 16;
  int n0 = nt * 64;
  const short8* A8 = (const short8*)o_lnb + (size_t)(m0 >> 4) * 16 * 64;
  const short8* B8 = (const short8*)w1b;

  float4v acc[4];
#pragma unroll
  for (int nf = 0; nf < 4; ++nf) acc[nf] = (float4v){0.f, 0.f, 0.f, 0.f};

#pragma unroll 4
  for (int c = 0; c < 16; ++c) {
    short8 a = A8[(size_t)c * 64 + lane];
#pragma unroll
    for (int nf = 0; nf < 4; ++nf) {
      short8 b = B8[((size_t)((n0 >> 4) + nf) * 16 + c) * 64 + lane];
      acc[nf] = __builtin_amdgcn_mfma_f32_16x16x32_bf16(a, b, acc[nf], 0, 0, 0);
    }
  }

#pragma unroll
  for (int nf = 0; nf < 4; ++nf) {
    int col = n0 + nf * 16 + lm;
    float bb = b1[col];
#pragma unroll
    for (int r = 0; r < 4; ++r) {
      int row = m0 + lq * 4 + r;
      h1b[pk(row, col, DI)] = f2b(fmaxf(acc[nf][r] + bb, 0.f));
    }
  }
}

// ---------------------------------------------------------------------------
// K4: GEMM2  ypart[ks] = h1 @ w2^T.  M=1024 N=512 K=2048, K-split x4. (r10)
// ---------------------------------------------------------------------------
__global__ __launch_bounds__(256) void gemm2_kernel(
    const unsigned short* __restrict__ h1b, const unsigned short* __restrict__ w2b,
    float* __restrict__ ypart) {
  int blk = blockIdx.x;
  int nt = blk & 7, mt = (blk >> 3) & 15, kslice = blk >> 7;
  int wv = threadIdx.x >> 6, lane = threadIdx.x & 63;
  int lm = lane & 15, lq = lane >> 4;

  int m0 = mt * 64 + wv * 16;
  int n0 = nt * 64;
  const short8* A8 = (const short8*)h1b + (size_t)(m0 >> 4) * 64 * 64;   // K/32=64
  const short8* B8 = (const short8*)w2b;

  float4v acc[4];
#pragma unroll
  for (int nf = 0; nf < 4; ++nf) acc[nf] = (float4v){0.f, 0.f, 0.f, 0.f};

#pragma unroll 4
  for (int ci = 0; ci < 16; ++ci) {
    int c = kslice * 16 + ci;
    short8 a = A8[(size_t)c * 64 + lane];
#pragma unroll
    for (int nf = 0; nf < 4; ++nf) {
      short8 b = B8[((size_t)((n0 >> 4) + nf) * 64 + c) * 64 + lane];
      acc[nf] = __builtin_amdgcn_mfma_f32_16x16x32_bf16(a, b, acc[nf], 0, 0, 0);
    }
  }

  float* outp = ypart + (size_t)kslice * SLICE;
#pragma unroll
  for (int nf = 0; nf < 4; ++nf) {
    int col = n0 + nf * 16 + lm;
#pragma unroll
    for (int r = 0; r < 4; ++r)
      outp[(size_t)(m0 + lq * 4 + r) * DD + col] = acc[nf][r];
  }
}

// ---------------------------------------------------------------------------
// K5: final LN:  y = LN(sum ypart + b2 + o_ln)*g + b.  (r10)
// ---------------------------------------------------------------------------
__global__ __launch_bounds__(256) void ln_final_kernel(
    const float* __restrict__ ypart, const float* __restrict__ o_ln,
    const float* __restrict__ b2, const float* __restrict__ fln_g,
    const float* __restrict__ fln_b, float* __restrict__ y_out) {
  int wv = threadIdx.x >> 6, lane = threadIdx.x & 63;
  int row = blockIdx.x * 4 + wv;

  const float* p0 = ypart + (size_t)row * DD;
  const float* ol = o_ln + (size_t)row * DD;
  float vals[8];
  float sum = 0.f, sq = 0.f;
#pragma unroll
  for (int k = 0; k < 8; ++k) {
    int d = lane + 64 * k;
    float v = p0[d] + p0[SLICE + d] + p0[2 * SLICE + d] + p0[3 * SLICE + d] +
              b2[d] + ol[d];
    vals[k] = v;
    sum += v;
    sq += v * v;
  }
#pragma unroll
  for (int off = 32; off > 0; off >>= 1) {
    sum += __shfl_xor(sum, off);
    sq  += __shfl_xor(sq, off);
  }
  float mu  = sum * (1.f / DD);
  float var = sq * (1.f / DD) - mu * mu;
  float rs  = rsqrtf(var + EPSN);
  float* yo = y_out + (size_t)row * DD;
#pragma unroll
  for (int k = 0; k < 8; ++k) {
    int d = lane + 64 * k;
    yo[d] = (vals[k] - mu) * rs * fln_g[d] + fln_b[d];
  }
}

extern "C" void kernel_launch(void* const* d_in, const int* in_sizes, int n_in,
                              void* d_out, int out_size, void* d_ws, size_t ws_size,
                              hipStream_t stream) {
  const float* x     = (const float*)d_in[0];
  const int*   mask  = (const int*)d_in[1];
  const float* w     = (const float*)d_in[2];
  const float* v_w   = (const float*)d_in[3];
  const float* ln_g  = (const float*)d_in[4];
  const float* ln_b  = (const float*)d_in[5];
  const float* w1    = (const float*)d_in[6];
  const float* b1    = (const float*)d_in[7];
  const float* w2    = (const float*)d_in[8];
  const float* b2    = (const float*)d_in[9];
  const float* fln_g = (const float*)d_in[10];
  const float* fln_b = (const float*)d_in[11];

  float* y    = (float*)d_out;
  float* attn = y + (size_t)BB * SS * HH * DD;

  // workspace layout (bytes)
  char* ws = (char*)d_ws;
  float*          o_ln   = (float*)(ws);                       // 2 MB
  unsigned short* o_lnb  = (unsigned short*)(ws + 2097152);    // 1 MB
  unsigned short* w1b    = (unsigned short*)(ws + 3145728);    // 2 MB
  unsigned short* w2b    = (unsigned short*)(ws + 5242880);    // 2 MB
  unsigned short* h1b    = (unsigned short*)(ws + 7340032);    // 4 MB
  float*          ypart  = (float*)(ws + 11534336);            // 8 MB (4 slices)
  unsigned short* v_wb   = (unsigned short*)(ws + 19922944);   // 512 KB
  float*          logits = (float*)(ws + 29884416);            // 512 KB

  pre_kernel<<<NLOGW_BLK + NCAST_BLK, 256, 0, stream>>>(
      x, mask, w, w1, w2, v_w, w1b, w2b, v_wb, logits);
  attn_v_ln_kernel<<<NAVL_BLK, 512, 0, stream>>>(
      x, logits, v_wb, ln_g, ln_b, attn, o_ln, o_lnb);
  gemm1_kernel<<<512, 256, 0, stream>>>(o_lnb, w1b, b1, h1b);
  gemm2_kernel<<<512, 256, 0, stream>>>(h1b, w2b, ypart);
  ln_final_kernel<<<256, 256, 0, stream>>>(ypart, o_ln, b2, fln_g, fln_b, y);
}